// Round 9
// baseline (837.720 us; speedup 1.0000x reference)
//
#include <hip/hip_runtime.h>
#include <hip/hip_bf16.h>

#define B_ 4
#define T_ 2048
#define D_ 512
#define H_ 8
#define FF_ 2048
#define L_ 4
#define NTOK 8192        // B_*T_
#define EPS_ 1e-5f

typedef __hip_bfloat16 bf16;
typedef __attribute__((ext_vector_type(8))) short short8;
typedef __attribute__((ext_vector_type(4))) float floatx4;

__device__ __forceinline__ float bf2f(short s) {
    union { unsigned u; float f; } cv;
    cv.u = ((unsigned)(unsigned short)s) << 16;
    return cv.f;
}
__device__ __forceinline__ short f2bs(float f) {
    union { bf16 b; short s; } cv;
    cv.b = __float2bfloat16(f);
    return cv.s;
}

// ---------------------------------------------------------------------------
// Fused one-shot prep: all four weight tensors -> bf16 (contiguous dst), plus
// proj_w transpose. Segment boundaries in float4 units:
//   qkv_w 786432 | out_w 262144 | ff1_w 1048576 | ff2_w 1048576  (sum 3145728)
// Blocks >= 12288 handle the 16384-elem pw transpose.
// ---------------------------------------------------------------------------
__global__ __launch_bounds__(256) void prep_kernel(
    const float* __restrict__ s0, const float* __restrict__ s1,
    const float* __restrict__ s2, const float* __restrict__ s3,
    bf16* __restrict__ dst, const float* __restrict__ pw, float* __restrict__ pwT)
{
    int bid = blockIdx.x;
    if (bid >= 12288) {
        int idx = (bid - 12288) * 256 + threadIdx.x;   // 0..16383
        int d = idx >> 5, k = idx & 31;
        pwT[k * D_ + d] = pw[idx];
        return;
    }
    long i = (long)bid * 256 + threadIdx.x;            // float4 index
    const float* src; long off;
    if (i < 786432)       { src = s0; off = i; }
    else if (i < 1048576) { src = s1; off = i - 786432; }
    else if (i < 2097152) { src = s2; off = i - 1048576; }
    else                  { src = s3; off = i - 2097152; }
    float4 v = ((const float4*)src)[off];
    union { short s[4]; uint2 u; } pk;
    pk.s[0] = f2bs(v.x); pk.s[1] = f2bs(v.y);
    pk.s[2] = f2bs(v.z); pk.s[3] = f2bs(v.w);
    *(uint2*)((short*)dst + i * 4) = pk.u;
}

// ---------------------------------------------------------------------------
// Input projection: 16 tokens/block, thread owns 2 cols; weights in VGPRs.
// ---------------------------------------------------------------------------
__global__ __launch_bounds__(256) void proj_kernel(
    const float* __restrict__ feat, const float* __restrict__ pwT,
    const float* __restrict__ pb, const float* __restrict__ pe,
    bf16* __restrict__ xb)
{
    __shared__ float fs[16][32];
    int tok0 = blockIdx.x * 16;
    int tid = threadIdx.x;
    {
        float2 v = ((const float2*)(feat + (size_t)tok0 * 32))[tid];
        fs[tid >> 4][(tid & 15) * 2]     = v.x;
        fs[tid >> 4][(tid & 15) * 2 + 1] = v.y;
    }
    int d0 = tid * 2;
    float w0[32], w1[32];
    #pragma unroll
    for (int k = 0; k < 32; k++) {
        float2 wv = *(const float2*)(pwT + k * D_ + d0);
        w0[k] = wv.x; w1[k] = wv.y;
    }
    float2 pbv = *(const float2*)(pb + d0);
    __syncthreads();
    #pragma unroll 4
    for (int tok = 0; tok < 16; tok++) {
        int t = (tok0 + tok) & (T_ - 1);
        float s0 = pbv.x, s1 = pbv.y;
        #pragma unroll
        for (int k = 0; k < 32; k++) {
            float f = fs[tok][k];
            s0 += f * w0[k]; s1 += f * w1[k];
        }
        float2 pev = *(const float2*)(pe + (size_t)t * D_ + d0);
        s0 += pev.x; s1 += pev.y;
        size_t o = (size_t)(tok0 + tok) * D_ + d0;
        union { struct { short a, b; } s; unsigned u; } pk;
        pk.s.a = f2bs(s0); pk.s.b = f2bs(s1);
        *(unsigned*)((short*)xb + o) = pk.u;
    }
}

// ---------------------------------------------------------------------------
// bf16 MFMA GEMM v3: A fragments DIRECT from global (L2-resident, the MFMA
// A-layout maps to 16 full cache lines per instr), B via LDS ping-pong with
// register-staged 2-deep prefetch. Rebalances pipes: LDS issue/iter drops
// 144 -> 72 cyc vs 78 cyc MFMA (was the structural cap at ~500 TF).
// C_z[M,N] = A[M,kbase:kbase+Kloc] @ W[N,same]^T (+bias if z==0), split-K via
// gridDim.z, partial z at Cb + z*M*N (bf16). 128x128 tile, BK=32, 4 waves.
// ---------------------------------------------------------------------------
template <int RELU>
__global__ __launch_bounds__(256) void gemm_bf16_kernel(
    const short* __restrict__ A, const short* __restrict__ W,
    const float* __restrict__ bias, bf16* __restrict__ Cb,
    int M, int N, int Kstride, int Kloc)
{
    __shared__ __align__(16) short lds[128 * 136];   // epilogue tile; K-loop uses first 16 KB
    int bm = blockIdx.y * 128, bn = blockIdx.x * 128;
    int kbase = blockIdx.z * Kloc;
    int tid = threadIdx.x;
    int w = tid >> 6, lane = tid & 63;
    int wm = (w >> 1) * 64, wn = (w & 1) * 64;

    floatx4 acc[4][4];
    #pragma unroll
    for (int i = 0; i < 4; i++)
        #pragma unroll
        for (int j = 0; j < 4; j++)
            acc[i][j] = (floatx4){0.f, 0.f, 0.f, 0.f};

    int lrow = lane & 15, lk = lane >> 4;

    // A fragment base pointers (direct global, MFMA A-layout)
    const short* Ap[4];
    #pragma unroll
    for (int i = 0; i < 4; i++)
        Ap[i] = A + (size_t)(bm + wm + i * 16 + lrow) * Kstride + kbase + lk * 8;

    // B staging map (unchanged, XOR swizzle, 2-way-free banks)
    int r0 = tid >> 2;
    int c0 = tid & 3;
    int slot = (c0 ^ ((r0 >> 1) & 3)) * 8;
    const short* Brow0 = W + (size_t)(bn + r0) * Kstride + kbase + c0 * 8;
    const short* Brow1 = W + (size_t)(bn + r0 + 64) * Kstride + kbase + c0 * 8;

    short8 eb0, eb1, ob0, ob1;                 // B stage regs (iters it, it+1)
    eb0 = *(const short8*)(Brow0);       eb1 = *(const short8*)(Brow1);
    ob0 = *(const short8*)(Brow0 + 32);  ob1 = *(const short8*)(Brow1 + 32);

    short8 afe[4], afo[4];                     // A frag regs (even/odd iters)
    #pragma unroll
    for (int i = 0; i < 4; i++) afe[i] = *(const short8*)(Ap[i]);

    int nIter = Kloc >> 5;                     // even for all shapes used
    for (int it = 0; it < nIter; it += 2) {
        #pragma unroll
        for (int half = 0; half < 2; half++) {
            short* Bs = lds + half * 4096;
            if (half == 0) {
                *(short8*)&Bs[r0 * 32 + slot] = eb0;
                *(short8*)&Bs[(r0 + 64) * 32 + slot] = eb1;
            } else {
                *(short8*)&Bs[r0 * 32 + slot] = ob0;
                *(short8*)&Bs[(r0 + 64) * 32 + slot] = ob1;
            }
            __syncthreads();
            // prefetch B for iter it+half+2 (precise vmcnt via reg dependency)
            int kn = (it + half + 2) * 32;
            if (kn < Kloc) {
                if (half == 0) {
                    eb0 = *(const short8*)(Brow0 + kn);
                    eb1 = *(const short8*)(Brow1 + kn);
                } else {
                    ob0 = *(const short8*)(Brow0 + kn);
                    ob1 = *(const short8*)(Brow1 + kn);
                }
            }
            // prefetch A frags for iter it+half+1 (lands one compute phase later)
            int ka = (it + half + 1) * 32;
            if (ka < Kloc) {
                if (half == 0) {
                    #pragma unroll
                    for (int i = 0; i < 4; i++) afo[i] = *(const short8*)(Ap[i] + ka);
                } else {
                    #pragma unroll
                    for (int i = 0; i < 4; i++) afe[i] = *(const short8*)(Ap[i] + ka);
                }
            }
            // compute iter it+half: A from regs, B from LDS
            short8 bfr[4];
            #pragma unroll
            for (int j = 0; j < 4; j++) {
                int nn = wn + j * 16 + lrow;
                bfr[j] = *(const short8*)&Bs[nn * 32 + ((lk ^ ((nn >> 1) & 3)) * 8)];
            }
            #pragma unroll
            for (int i = 0; i < 4; i++)
                #pragma unroll
                for (int j = 0; j < 4; j++)
                    acc[i][j] = __builtin_amdgcn_mfma_f32_16x16x32_bf16(
                        (half == 0) ? afe[i] : afo[i], bfr[j], acc[i][j], 0, 0, 0);
        }
    }

    __syncthreads();

    int cl = lane & 15, rq = lane >> 4;
    bool z0 = (blockIdx.z == 0);
    #pragma unroll
    for (int i = 0; i < 4; i++) {
        #pragma unroll
        for (int j = 0; j < 4; j++) {
            int col = wn + j * 16 + cl;
            float bv = z0 ? bias[bn + col] : 0.f;
            #pragma unroll
            for (int r = 0; r < 4; r++) {
                int row = wm + i * 16 + rq * 4 + r;
                float v = acc[i][j][r] + bv;
                if (RELU) v = fmaxf(v, 0.f);
                lds[row * 136 + col] = f2bs(v);
            }
        }
    }
    __syncthreads();

    bf16* Cz = Cb + (size_t)blockIdx.z * M * N;
    #pragma unroll
    for (int s = 0; s < 8; s++) {
        int idx = tid + 256 * s;
        int r = idx >> 4, c8 = (idx & 15) * 8;
        short8 v = *(const short8*)&lds[r * 136 + c8];
        *(short8*)((short*)Cz + (size_t)(bm + r) * N + bn + c8) = v;
    }
}

// ---------------------------------------------------------------------------
// MFMA flash attention, banded window +-128. One block per (b, h, 64-q tile).
// No online max (scores provably tiny); p = exp(scale*s), masked -> 0.
// ---------------------------------------------------------------------------
__global__ __launch_bounds__(256, 4) void attn_kernel(
    const short* __restrict__ qkv, bf16* __restrict__ out)
{
    __shared__ __align__(16) short Qs[64 * 72];
    __shared__ __align__(16) short Ks[64 * 72];
    __shared__ __align__(16) short Vt[64 * 72];
    __shared__ __align__(16) short Ps[64 * 72];

    int q0 = blockIdx.x * 64;
    int bh = blockIdx.y;
    int b = bh >> 3, h = bh & 7;
    int tid = threadIdx.x;
    int w = tid >> 6, lane = tid & 63;
    int col = lane & 15, quad = lane >> 4;

    const size_t base = (size_t)b * T_ * 3 * D_;
    const int roww = 3 * D_;
    const int qoff = h * 64, koff = D_ + h * 64, voff = 2 * D_ + h * 64;

    #pragma unroll
    for (int i = 0; i < 2; i++) {
        int idx = tid + 256 * i;
        int r = idx >> 3, c8 = (idx & 7) * 8;
        *(short8*)&Qs[r * 72 + c8] =
            *(const short8*)(qkv + base + (size_t)(q0 + r) * roww + qoff + c8);
    }

    float l_r[4] = {0.f, 0.f, 0.f, 0.f};
    floatx4 Oacc[4];
    #pragma unroll
    for (int j = 0; j < 4; j++) Oacc[j] = (floatx4){0.f, 0.f, 0.f, 0.f};

    int klo = max(0, q0 - 128), khi = min(T_, q0 + 192);
    const float scale = 0.125f;
    int qrow = q0 + w * 16 + quad * 4;

    for (int kt = klo; kt < khi; kt += 64) {
        __syncthreads();   // B1
        #pragma unroll
        for (int i = 0; i < 2; i++) {
            int idx = tid + 256 * i;
            int r = idx >> 3, c8 = (idx & 7) * 8;
            *(short8*)&Ks[r * 72 + c8] =
                *(const short8*)(qkv + base + (size_t)(kt + r) * roww + koff + c8);
            short8 v = *(const short8*)(qkv + base + (size_t)(kt + r) * roww + voff + c8);
            #pragma unroll
            for (int u = 0; u < 8; u++) Vt[(c8 + u) * 72 + r] = v[u];
        }
        __syncthreads();   // B2

        short8 aq0 = *(const short8*)&Qs[(w * 16 + col) * 72 + quad * 8];
        short8 aq1 = *(const short8*)&Qs[(w * 16 + col) * 72 + 32 + quad * 8];
        floatx4 Sacc[4];
        #pragma unroll
        for (int j = 0; j < 4; j++) {
            short8 bk0 = *(const short8*)&Ks[(j * 16 + col) * 72 + quad * 8];
            short8 bk1 = *(const short8*)&Ks[(j * 16 + col) * 72 + 32 + quad * 8];
            floatx4 s = (floatx4){0.f, 0.f, 0.f, 0.f};
            s = __builtin_amdgcn_mfma_f32_16x16x32_bf16(aq0, bk0, s, 0, 0, 0);
            s = __builtin_amdgcn_mfma_f32_16x16x32_bf16(aq1, bk1, s, 0, 0, 0);
            Sacc[j] = s;
        }

        float ps[4] = {0.f, 0.f, 0.f, 0.f};
        #pragma unroll
        for (int j = 0; j < 4; j++) {
            int key = kt + j * 16 + col;
            #pragma unroll
            for (int r = 0; r < 4; r++) {
                int dj = key - (qrow + r);
                float p = (dj < -128 || dj > 128) ? 0.f : __expf(Sacc[j][r] * scale);
                ps[r] += p;
                Ps[(w * 16 + quad * 4 + r) * 72 + j * 16 + col] = f2bs(p);
            }
        }
        #pragma unroll
        for (int off = 1; off < 16; off <<= 1)
            #pragma unroll
            for (int r = 0; r < 4; r++)
                ps[r] += __shfl_xor(ps[r], off);
        #pragma unroll
        for (int r = 0; r < 4; r++) l_r[r] += ps[r];

        __syncthreads();   // B3

        short8 ap0 = *(const short8*)&Ps[(w * 16 + col) * 72 + quad * 8];
        short8 ap1 = *(const short8*)&Ps[(w * 16 + col) * 72 + 32 + quad * 8];
        #pragma unroll
        for (int j = 0; j < 4; j++) {
            short8 bv0 = *(const short8*)&Vt[(j * 16 + col) * 72 + quad * 8];
            short8 bv1 = *(const short8*)&Vt[(j * 16 + col) * 72 + 32 + quad * 8];
            Oacc[j] = __builtin_amdgcn_mfma_f32_16x16x32_bf16(ap0, bv0, Oacc[j], 0, 0, 0);
            Oacc[j] = __builtin_amdgcn_mfma_f32_16x16x32_bf16(ap1, bv1, Oacc[j], 0, 0, 0);
        }
    }

    float invl[4];
    #pragma unroll
    for (int r = 0; r < 4; r++) invl[r] = 1.0f / l_r[r];
    #pragma unroll
    for (int j = 0; j < 4; j++)
        #pragma unroll
        for (int r = 0; r < 4; r++)
            out[(size_t)(b * T_ + qrow + r) * D_ + h * 64 + j * 16 + col] =
                __float2bfloat16(Oacc[j][r] * invl[r]);
}

// ---------------------------------------------------------------------------
// Fused residual + split-K combine + LayerNorm, all-bf16 streams.
// ---------------------------------------------------------------------------
__global__ __launch_bounds__(256) void add_ln_kernel(
    const short* __restrict__ xb, const short* __restrict__ d0,
    const short* __restrict__ d1,
    const float* __restrict__ g, const float* __restrict__ bta,
    bf16* __restrict__ outb, float* __restrict__ outf)
{
    int wave = threadIdx.x >> 6, lane = threadIdx.x & 63;
    int row = blockIdx.x * 4 + wave;
    int c0 = lane * 8;
    size_t o = (size_t)row * D_ + c0;
    short8 xv = *(const short8*)(xb + o);
    short8 a0 = *(const short8*)(d0 + o);
    short8 a1 = *(const short8*)(d1 + o);
    float v[8];
    float s = 0.f;
    #pragma unroll
    for (int i = 0; i < 8; i++) {
        v[i] = bf2f(xv[i]) + bf2f(a0[i]) + bf2f(a1[i]);
        s += v[i];
    }
    #pragma unroll
    for (int off = 32; off > 0; off >>= 1) s += __shfl_xor(s, off);
    float mean = s * (1.0f / D_);
    float var = 0.f;
    #pragma unroll
    for (int i = 0; i < 8; i++) { float c = v[i] - mean; var += c * c; }
    #pragma unroll
    for (int off = 32; off > 0; off >>= 1) var += __shfl_xor(var, off);
    float inv = rsqrtf(var * (1.0f / D_) + EPS_);
    float4 g0 = *(const float4*)(g + c0), g1 = *(const float4*)(g + c0 + 4);
    float4 b0 = *(const float4*)(bta + c0), b1 = *(const float4*)(bta + c0 + 4);
    float ov[8];
    ov[0] = (v[0] - mean) * inv * g0.x + b0.x;
    ov[1] = (v[1] - mean) * inv * g0.y + b0.y;
    ov[2] = (v[2] - mean) * inv * g0.z + b0.z;
    ov[3] = (v[3] - mean) * inv * g0.w + b0.w;
    ov[4] = (v[4] - mean) * inv * g1.x + b1.x;
    ov[5] = (v[5] - mean) * inv * g1.y + b1.y;
    ov[6] = (v[6] - mean) * inv * g1.z + b1.z;
    ov[7] = (v[7] - mean) * inv * g1.w + b1.w;
    short8 ob;
    #pragma unroll
    for (int i = 0; i < 8; i++) ob[i] = f2bs(ov[i]);
    *(short8*)((short*)outb + o) = ob;
    if (outf) {
        *(float4*)(outf + o) = make_float4(ov[0], ov[1], ov[2], ov[3]);
        *(float4*)(outf + o + 4) = make_float4(ov[4], ov[5], ov[6], ov[7]);
    }
}

// ---------------------------------------------------------------------------
extern "C" void kernel_launch(void* const* d_in, const int* in_sizes, int n_in,
                              void* d_out, int out_size, void* d_ws, size_t ws_size,
                              hipStream_t stream)
{
    const float* feat    = (const float*)d_in[0];
    const float* proj_w  = (const float*)d_in[2];
    const float* proj_b  = (const float*)d_in[3];
    const float* pos_enc = (const float*)d_in[4];
    const float* qkv_w   = (const float*)d_in[5];
    const float* qkv_b   = (const float*)d_in[6];
    const float* out_w   = (const float*)d_in[7];
    const float* out_b   = (const float*)d_in[8];
    const float* ff1_w   = (const float*)d_in[9];
    const float* ff1_b   = (const float*)d_in[10];
    const float* ff2_w   = (const float*)d_in[11];
    const float* ff2_b   = (const float*)d_in[12];
    const float* ln1_g   = (const float*)d_in[13];
    const float* ln1_b   = (const float*)d_in[14];
    const float* ln2_g   = (const float*)d_in[15];
    const float* ln2_b   = (const float*)d_in[16];

    char* p = (char*)d_ws;
    float* pwT  = (float*)p;  p += (size_t)32 * D_ * 4;
    bf16* xb    = (bf16*)p;   p += (size_t)NTOK * D_ * 2;
    bf16* dpar  = (bf16*)p;   p += (size_t)2 * NTOK * D_ * 2;   // split-K partials
    bf16* qkvb  = (bf16*)p;   p += (size_t)NTOK * 3 * D_ * 2;
    bf16* hbuf  = (bf16*)p;   p += (size_t)NTOK * FF_ * 2;
    bf16* abuf  = (bf16*)p;   p += (size_t)NTOK * D_ * 2;
    // weights: contiguous wq | wo | w1 | w2 (prep_kernel relies on this)
    bf16* wq    = (bf16*)p;   p += (size_t)L_ * 3 * D_ * D_ * 2;
    bf16* wo    = (bf16*)p;   p += (size_t)L_ * D_ * D_ * 2;
    bf16* w1    = (bf16*)p;   p += (size_t)L_ * FF_ * D_ * 2;
    bf16* w2    = (bf16*)p;   p += (size_t)L_ * D_ * FF_ * 2;
    float* outp = (float*)d_out;

    prep_kernel<<<12288 + 64, 256, 0, stream>>>(
        qkv_w, out_w, ff1_w, ff2_w, wq, proj_w, pwT);

    proj_kernel<<<NTOK / 16, 256, 0, stream>>>(feat, pwT, proj_b, pos_enc, xb);

    for (int l = 0; l < L_; l++) {
        // QKV projection (unsplit)
        gemm_bf16_kernel<0><<<dim3(3 * D_ / 128, NTOK / 128, 1), 256, 0, stream>>>(
            (const short*)xb, (const short*)(wq + (size_t)l * 3 * D_ * D_),
            qkv_b + (size_t)l * 3 * D_, qkvb, NTOK, 3 * D_, D_, D_);
        attn_kernel<<<dim3(T_ / 64, B_ * H_), 256, 0, stream>>>((const short*)qkvb, abuf);
        // out-proj, split-K x2
        gemm_bf16_kernel<0><<<dim3(D_ / 128, NTOK / 128, 2), 256, 0, stream>>>(
            (const short*)abuf, (const short*)(wo + (size_t)l * D_ * D_),
            out_b + (size_t)l * D_, dpar, NTOK, D_, D_, D_ / 2);
        add_ln_kernel<<<NTOK / 4, 256, 0, stream>>>(
            (const short*)xb, (const short*)dpar, (const short*)(dpar + (size_t)NTOK * D_),
            ln1_g + (size_t)l * D_, ln1_b + (size_t)l * D_, xb, nullptr);
        // FF1 + ReLU (unsplit)
        gemm_bf16_kernel<1><<<dim3(FF_ / 128, NTOK / 128, 1), 256, 0, stream>>>(
            (const short*)xb, (const short*)(w1 + (size_t)l * FF_ * D_),
            ff1_b + (size_t)l * FF_, hbuf, NTOK, FF_, D_, D_);
        // FF2, split-K x2
        gemm_bf16_kernel<0><<<dim3(D_ / 128, NTOK / 128, 2), 256, 0, stream>>>(
            (const short*)hbuf, (const short*)(w2 + (size_t)l * D_ * FF_),
            ff2_b + (size_t)l * D_, dpar, NTOK, D_, FF_, FF_ / 2);
        float* dst = (l == L_ - 1) ? outp : nullptr;
        add_ln_kernel<<<NTOK / 4, 256, 0, stream>>>(
            (const short*)xb, (const short*)dpar, (const short*)(dpar + (size_t)NTOK * D_),
            ln2_g + (size_t)l * D_, ln2_b + (size_t)l * D_, xb, dst);
    }
}

// Round 10
// 617.784 us; speedup vs baseline: 1.3560x; 1.3560x over previous
//
#include <hip/hip_runtime.h>
#include <hip/hip_bf16.h>

#define B_ 4
#define T_ 2048
#define D_ 512
#define H_ 8
#define FF_ 2048
#define L_ 4
#define NTOK 8192        // B_*T_
#define EPS_ 1e-5f

typedef __hip_bfloat16 bf16;
typedef __attribute__((ext_vector_type(8))) short short8;
typedef __attribute__((ext_vector_type(4))) float floatx4;

__device__ __forceinline__ float bf2f(short s) {
    union { unsigned u; float f; } cv;
    cv.u = ((unsigned)(unsigned short)s) << 16;
    return cv.f;
}
__device__ __forceinline__ short f2bs(float f) {
    union { bf16 b; short s; } cv;
    cv.b = __float2bfloat16(f);
    return cv.s;
}

// XCD-aware swizzle: flat dispatch id -> logical id such that each XCD
// (id % 8, per dispatch round-robin) owns a CONTIGUOUS logical range ->
// per-XCD L2 working set shrinks below 4 MB. tot must be divisible by 8.
__device__ __forceinline__ int xcd_swizzle(int id, int tot) {
    return (id & 7) * (tot >> 3) + (id >> 3);
}

// ---------------------------------------------------------------------------
// Fused one-shot prep: all four weight tensors -> bf16 (contiguous dst), plus
// proj_w transpose. Segment boundaries in float4 units:
//   qkv_w 786432 | out_w 262144 | ff1_w 1048576 | ff2_w 1048576  (sum 3145728)
// Blocks >= 12288 handle the 16384-elem pw transpose.
// ---------------------------------------------------------------------------
__global__ __launch_bounds__(256) void prep_kernel(
    const float* __restrict__ s0, const float* __restrict__ s1,
    const float* __restrict__ s2, const float* __restrict__ s3,
    bf16* __restrict__ dst, const float* __restrict__ pw, float* __restrict__ pwT)
{
    int bid = blockIdx.x;
    if (bid >= 12288) {
        int idx = (bid - 12288) * 256 + threadIdx.x;   // 0..16383
        int d = idx >> 5, k = idx & 31;
        pwT[k * D_ + d] = pw[idx];
        return;
    }
    long i = (long)bid * 256 + threadIdx.x;            // float4 index
    const float* src; long off;
    if (i < 786432)       { src = s0; off = i; }
    else if (i < 1048576) { src = s1; off = i - 786432; }
    else if (i < 2097152) { src = s2; off = i - 1048576; }
    else                  { src = s3; off = i - 2097152; }
    float4 v = ((const float4*)src)[off];
    union { short s[4]; uint2 u; } pk;
    pk.s[0] = f2bs(v.x); pk.s[1] = f2bs(v.y);
    pk.s[2] = f2bs(v.z); pk.s[3] = f2bs(v.w);
    *(uint2*)((short*)dst + i * 4) = pk.u;
}

// ---------------------------------------------------------------------------
// Input projection: 16 tokens/block, thread owns 2 cols; weights in VGPRs.
// ---------------------------------------------------------------------------
__global__ __launch_bounds__(256) void proj_kernel(
    const float* __restrict__ feat, const float* __restrict__ pwT,
    const float* __restrict__ pb, const float* __restrict__ pe,
    bf16* __restrict__ xb)
{
    __shared__ float fs[16][32];
    int tok0 = blockIdx.x * 16;
    int tid = threadIdx.x;
    {
        float2 v = ((const float2*)(feat + (size_t)tok0 * 32))[tid];
        fs[tid >> 4][(tid & 15) * 2]     = v.x;
        fs[tid >> 4][(tid & 15) * 2 + 1] = v.y;
    }
    int d0 = tid * 2;
    float w0[32], w1[32];
    #pragma unroll
    for (int k = 0; k < 32; k++) {
        float2 wv = *(const float2*)(pwT + k * D_ + d0);
        w0[k] = wv.x; w1[k] = wv.y;
    }
    float2 pbv = *(const float2*)(pb + d0);
    __syncthreads();
    #pragma unroll 4
    for (int tok = 0; tok < 16; tok++) {
        int t = (tok0 + tok) & (T_ - 1);
        float s0 = pbv.x, s1 = pbv.y;
        #pragma unroll
        for (int k = 0; k < 32; k++) {
            float f = fs[tok][k];
            s0 += f * w0[k]; s1 += f * w1[k];
        }
        float2 pev = *(const float2*)(pe + (size_t)t * D_ + d0);
        s0 += pev.x; s1 += pev.y;
        size_t o = (size_t)(tok0 + tok) * D_ + d0;
        union { struct { short a, b; } s; unsigned u; } pk;
        pk.s.a = f2bs(s0); pk.s.b = f2bs(s1);
        *(unsigned*)((short*)xb + o) = pk.u;
    }
}

// ---------------------------------------------------------------------------
// bf16 MFMA GEMM (R8 structure, reverted from the R9 A-direct regression):
// register-staged 2-deep prefetch for BOTH A and B, LDS ping-pong, one
// barrier/iter, XOR chunk swizzle, split-K via gridDim.z, XCD-aware grid
// swizzle for per-XCD L2 locality. RELU only valid unsplit.
// ---------------------------------------------------------------------------
template <int RELU>
__global__ __launch_bounds__(256) void gemm_bf16_kernel(
    const short* __restrict__ A, const short* __restrict__ W,
    const float* __restrict__ bias, bf16* __restrict__ Cb,
    int M, int N, int Kstride, int Kloc)
{
    __shared__ __align__(16) short lds[128 * 136];   // 34816 B; K-loop uses 32768 B
    int nx = gridDim.x;
    int id = blockIdx.y * nx + blockIdx.x;
    int lid = xcd_swizzle(id, nx * gridDim.y);
    int bm = (lid / nx) * 128, bn = (lid % nx) * 128;
    int kbase = blockIdx.z * Kloc;
    int tid = threadIdx.x;
    int w = tid >> 6, lane = tid & 63;
    int wm = (w >> 1) * 64, wn = (w & 1) * 64;

    floatx4 acc[4][4];
    #pragma unroll
    for (int i = 0; i < 4; i++)
        #pragma unroll
        for (int j = 0; j < 4; j++)
            acc[i][j] = (floatx4){0.f, 0.f, 0.f, 0.f};

    int r0 = tid >> 2;
    int c0 = tid & 3;
    int slot = (c0 ^ ((r0 >> 1) & 3)) * 8;
    const short* Arow0 = A + (size_t)(bm + r0) * Kstride + kbase + c0 * 8;
    const short* Arow1 = A + (size_t)(bm + r0 + 64) * Kstride + kbase + c0 * 8;
    const short* Brow0 = W + (size_t)(bn + r0) * Kstride + kbase + c0 * 8;
    const short* Brow1 = W + (size_t)(bn + r0 + 64) * Kstride + kbase + c0 * 8;

    int lrow = lane & 15, lk = lane >> 4;

    short8 ea0, ea1, eb0, eb1;
    short8 oa0, oa1, ob0, ob1;
    ea0 = *(const short8*)(Arow0);       ea1 = *(const short8*)(Arow1);
    eb0 = *(const short8*)(Brow0);       eb1 = *(const short8*)(Brow1);
    oa0 = *(const short8*)(Arow0 + 32);  oa1 = *(const short8*)(Arow1 + 32);
    ob0 = *(const short8*)(Brow0 + 32);  ob1 = *(const short8*)(Brow1 + 32);

    int nIter = Kloc >> 5;                  // even for all shapes used
    for (int it = 0; it < nIter; it += 2) {
        #pragma unroll
        for (int half = 0; half < 2; half++) {
            short* As = lds + half * 8192;
            short* Bs = lds + half * 8192 + 4096;
            if (half == 0) {
                *(short8*)&As[r0 * 32 + slot] = ea0;
                *(short8*)&As[(r0 + 64) * 32 + slot] = ea1;
                *(short8*)&Bs[r0 * 32 + slot] = eb0;
                *(short8*)&Bs[(r0 + 64) * 32 + slot] = eb1;
            } else {
                *(short8*)&As[r0 * 32 + slot] = oa0;
                *(short8*)&As[(r0 + 64) * 32 + slot] = oa1;
                *(short8*)&Bs[r0 * 32 + slot] = ob0;
                *(short8*)&Bs[(r0 + 64) * 32 + slot] = ob1;
            }
            __syncthreads();
            int kn = (it + half + 2) * 32;
            if (kn < Kloc) {
                if (half == 0) {
                    ea0 = *(const short8*)(Arow0 + kn);
                    ea1 = *(const short8*)(Arow1 + kn);
                    eb0 = *(const short8*)(Brow0 + kn);
                    eb1 = *(const short8*)(Brow1 + kn);
                } else {
                    oa0 = *(const short8*)(Arow0 + kn);
                    oa1 = *(const short8*)(Arow1 + kn);
                    ob0 = *(const short8*)(Brow0 + kn);
                    ob1 = *(const short8*)(Brow1 + kn);
                }
            }
            short8 af[4], bfr[4];
            #pragma unroll
            for (int i = 0; i < 4; i++) {
                int rr = wm + i * 16 + lrow;
                af[i] = *(const short8*)&As[rr * 32 + ((lk ^ ((rr >> 1) & 3)) * 8)];
                int nn = wn + i * 16 + lrow;
                bfr[i] = *(const short8*)&Bs[nn * 32 + ((lk ^ ((nn >> 1) & 3)) * 8)];
            }
            #pragma unroll
            for (int i = 0; i < 4; i++)
                #pragma unroll
                for (int j = 0; j < 4; j++)
                    acc[i][j] = __builtin_amdgcn_mfma_f32_16x16x32_bf16(
                        af[i], bfr[j], acc[i][j], 0, 0, 0);
        }
    }

    __syncthreads();

    int cl = lane & 15, rq = lane >> 4;
    bool z0 = (blockIdx.z == 0);
    #pragma unroll
    for (int i = 0; i < 4; i++) {
        #pragma unroll
        for (int j = 0; j < 4; j++) {
            int col = wn + j * 16 + cl;
            float bv = z0 ? bias[bn + col] : 0.f;
            #pragma unroll
            for (int r = 0; r < 4; r++) {
                int row = wm + i * 16 + rq * 4 + r;
                float v = acc[i][j][r] + bv;
                if (RELU) v = fmaxf(v, 0.f);
                lds[row * 136 + col] = f2bs(v);
            }
        }
    }
    __syncthreads();

    bf16* Cz = Cb + (size_t)blockIdx.z * M * N;
    #pragma unroll
    for (int s = 0; s < 8; s++) {
        int idx = tid + 256 * s;
        int r = idx >> 4, c8 = (idx & 15) * 8;
        short8 v = *(const short8*)&lds[r * 136 + c8];
        *(short8*)((short*)Cz + (size_t)(bm + r) * N + bn + c8) = v;
    }
}

// ---------------------------------------------------------------------------
// MFMA flash attention, banded window +-128. One block per (b, h, 64-q tile).
// No online max (scores provably tiny); p = exp(scale*s), masked -> 0.
// K/V REGISTER PREFETCH: next k-tile's loads are issued right after this
// tile's LDS write -> in flight across the full S+softmax+PV phase, removing
// the per-ktile exposed L2 latency. XCD-swizzled grid: each XCD owns 4
// contiguous (b,h) panels -> ~1 MB KV working set per XCD L2.
// ---------------------------------------------------------------------------
__global__ __launch_bounds__(256, 4) void attn_kernel(
    const short* __restrict__ qkv, bf16* __restrict__ out)
{
    __shared__ __align__(16) short Qs[64 * 72];
    __shared__ __align__(16) short Ks[64 * 72];
    __shared__ __align__(16) short Vt[64 * 72];
    __shared__ __align__(16) short Ps[64 * 72];

    int id = blockIdx.y * 32 + blockIdx.x;          // nx = T_/64 = 32
    int lid = xcd_swizzle(id, 32 * B_ * H_);
    int q0 = (lid % 32) * 64;
    int bh = lid / 32;
    int b = bh >> 3, h = bh & 7;
    int tid = threadIdx.x;
    int w = tid >> 6, lane = tid & 63;
    int col = lane & 15, quad = lane >> 4;

    const size_t base = (size_t)b * T_ * 3 * D_;
    const int roww = 3 * D_;
    const int qoff = h * 64, koff = D_ + h * 64, voff = 2 * D_ + h * 64;

    // staging map for K/V: thread covers rows r_s and r_s in second half
    int r_s = tid >> 3, c8_s = (tid & 7) * 8;       // i=0: rows 0..31
    int r_s2 = r_s + 32;                            // i=1: rows 32..63

    #pragma unroll
    for (int i = 0; i < 2; i++) {
        int idx = tid + 256 * i;
        int r = idx >> 3, c8 = (idx & 7) * 8;
        *(short8*)&Qs[r * 72 + c8] =
            *(const short8*)(qkv + base + (size_t)(q0 + r) * roww + qoff + c8);
    }

    float l_r[4] = {0.f, 0.f, 0.f, 0.f};
    floatx4 Oacc[4];
    #pragma unroll
    for (int j = 0; j < 4; j++) Oacc[j] = (floatx4){0.f, 0.f, 0.f, 0.f};

    int klo = max(0, q0 - 128), khi = min(T_, q0 + 192);
    const float scale = 0.125f;
    int qrow = q0 + w * 16 + quad * 4;

    // prologue: first K/V tile into registers
    short8 kreg0, kreg1, vreg0, vreg1;
    kreg0 = *(const short8*)(qkv + base + (size_t)(klo + r_s) * roww + koff + c8_s);
    kreg1 = *(const short8*)(qkv + base + (size_t)(klo + r_s2) * roww + koff + c8_s);
    vreg0 = *(const short8*)(qkv + base + (size_t)(klo + r_s) * roww + voff + c8_s);
    vreg1 = *(const short8*)(qkv + base + (size_t)(klo + r_s2) * roww + voff + c8_s);

    for (int kt = klo; kt < khi; kt += 64) {
        __syncthreads();   // B1: prev PV reads done; Ks/Vt/Ps free
        // write staged K/V regs to LDS
        *(short8*)&Ks[r_s * 72 + c8_s] = kreg0;
        *(short8*)&Ks[r_s2 * 72 + c8_s] = kreg1;
        #pragma unroll
        for (int u = 0; u < 8; u++) Vt[(c8_s + u) * 72 + r_s] = vreg0[u];
        #pragma unroll
        for (int u = 0; u < 8; u++) Vt[(c8_s + u) * 72 + r_s2] = vreg1[u];
        // issue next tile's loads (in flight across S+softmax+PV)
        int ktn = kt + 64;
        if (ktn < khi) {
            kreg0 = *(const short8*)(qkv + base + (size_t)(ktn + r_s) * roww + koff + c8_s);
            kreg1 = *(const short8*)(qkv + base + (size_t)(ktn + r_s2) * roww + koff + c8_s);
            vreg0 = *(const short8*)(qkv + base + (size_t)(ktn + r_s) * roww + voff + c8_s);
            vreg1 = *(const short8*)(qkv + base + (size_t)(ktn + r_s2) * roww + voff + c8_s);
        }
        __syncthreads();   // B2: K, Vt ready

        short8 aq0 = *(const short8*)&Qs[(w * 16 + col) * 72 + quad * 8];
        short8 aq1 = *(const short8*)&Qs[(w * 16 + col) * 72 + 32 + quad * 8];
        floatx4 Sacc[4];
        #pragma unroll
        for (int j = 0; j < 4; j++) {
            short8 bk0 = *(const short8*)&Ks[(j * 16 + col) * 72 + quad * 8];
            short8 bk1 = *(const short8*)&Ks[(j * 16 + col) * 72 + 32 + quad * 8];
            floatx4 s = (floatx4){0.f, 0.f, 0.f, 0.f};
            s = __builtin_amdgcn_mfma_f32_16x16x32_bf16(aq0, bk0, s, 0, 0, 0);
            s = __builtin_amdgcn_mfma_f32_16x16x32_bf16(aq1, bk1, s, 0, 0, 0);
            Sacc[j] = s;
        }

        float ps[4] = {0.f, 0.f, 0.f, 0.f};
        #pragma unroll
        for (int j = 0; j < 4; j++) {
            int key = kt + j * 16 + col;
            #pragma unroll
            for (int r = 0; r < 4; r++) {
                int dj = key - (qrow + r);
                float p = (dj < -128 || dj > 128) ? 0.f : __expf(Sacc[j][r] * scale);
                ps[r] += p;
                Ps[(w * 16 + quad * 4 + r) * 72 + j * 16 + col] = f2bs(p);
            }
        }
        #pragma unroll
        for (int off = 1; off < 16; off <<= 1)
            #pragma unroll
            for (int r = 0; r < 4; r++)
                ps[r] += __shfl_xor(ps[r], off);
        #pragma unroll
        for (int r = 0; r < 4; r++) l_r[r] += ps[r];

        __syncthreads();   // B3: Ps visible

        short8 ap0 = *(const short8*)&Ps[(w * 16 + col) * 72 + quad * 8];
        short8 ap1 = *(const short8*)&Ps[(w * 16 + col) * 72 + 32 + quad * 8];
        #pragma unroll
        for (int j = 0; j < 4; j++) {
            short8 bv0 = *(const short8*)&Vt[(j * 16 + col) * 72 + quad * 8];
            short8 bv1 = *(const short8*)&Vt[(j * 16 + col) * 72 + 32 + quad * 8];
            Oacc[j] = __builtin_amdgcn_mfma_f32_16x16x32_bf16(ap0, bv0, Oacc[j], 0, 0, 0);
            Oacc[j] = __builtin_amdgcn_mfma_f32_16x16x32_bf16(ap1, bv1, Oacc[j], 0, 0, 0);
        }
    }

    float invl[4];
    #pragma unroll
    for (int r = 0; r < 4; r++) invl[r] = 1.0f / l_r[r];
    #pragma unroll
    for (int j = 0; j < 4; j++)
        #pragma unroll
        for (int r = 0; r < 4; r++)
            out[(size_t)(b * T_ + qrow + r) * D_ + h * 64 + j * 16 + col] =
                __float2bfloat16(Oacc[j][r] * invl[r]);
}

// ---------------------------------------------------------------------------
// Fused residual + split-K combine + LayerNorm, all-bf16 streams.
// ---------------------------------------------------------------------------
__global__ __launch_bounds__(256) void add_ln_kernel(
    const short* __restrict__ xb, const short* __restrict__ d0,
    const short* __restrict__ d1,
    const float* __restrict__ g, const float* __restrict__ bta,
    bf16* __restrict__ outb, float* __restrict__ outf)
{
    int wave = threadIdx.x >> 6, lane = threadIdx.x & 63;
    int row = blockIdx.x * 4 + wave;
    int c0 = lane * 8;
    size_t o = (size_t)row * D_ + c0;
    short8 xv = *(const short8*)(xb + o);
    short8 a0 = *(const short8*)(d0 + o);
    short8 a1 = *(const short8*)(d1 + o);
    float v[8];
    float s = 0.f;
    #pragma unroll
    for (int i = 0; i < 8; i++) {
        v[i] = bf2f(xv[i]) + bf2f(a0[i]) + bf2f(a1[i]);
        s += v[i];
    }
    #pragma unroll
    for (int off = 32; off > 0; off >>= 1) s += __shfl_xor(s, off);
    float mean = s * (1.0f / D_);
    float var = 0.f;
    #pragma unroll
    for (int i = 0; i < 8; i++) { float c = v[i] - mean; var += c * c; }
    #pragma unroll
    for (int off = 32; off > 0; off >>= 1) var += __shfl_xor(var, off);
    float inv = rsqrtf(var * (1.0f / D_) + EPS_);
    float4 g0 = *(const float4*)(g + c0), g1 = *(const float4*)(g + c0 + 4);
    float4 b0 = *(const float4*)(bta + c0), b1 = *(const float4*)(bta + c0 + 4);
    float ov[8];
    ov[0] = (v[0] - mean) * inv * g0.x + b0.x;
    ov[1] = (v[1] - mean) * inv * g0.y + b0.y;
    ov[2] = (v[2] - mean) * inv * g0.z + b0.z;
    ov[3] = (v[3] - mean) * inv * g0.w + b0.w;
    ov[4] = (v[4] - mean) * inv * g1.x + b1.x;
    ov[5] = (v[5] - mean) * inv * g1.y + b1.y;
    ov[6] = (v[6] - mean) * inv * g1.z + b1.z;
    ov[7] = (v[7] - mean) * inv * g1.w + b1.w;
    short8 ob;
    #pragma unroll
    for (int i = 0; i < 8; i++) ob[i] = f2bs(ov[i]);
    *(short8*)((short*)outb + o) = ob;
    if (outf) {
        *(float4*)(outf + o) = make_float4(ov[0], ov[1], ov[2], ov[3]);
        *(float4*)(outf + o + 4) = make_float4(ov[4], ov[5], ov[6], ov[7]);
    }
}

// ---------------------------------------------------------------------------
extern "C" void kernel_launch(void* const* d_in, const int* in_sizes, int n_in,
                              void* d_out, int out_size, void* d_ws, size_t ws_size,
                              hipStream_t stream)
{
    const float* feat    = (const float*)d_in[0];
    const float* proj_w  = (const float*)d_in[2];
    const float* proj_b  = (const float*)d_in[3];
    const float* pos_enc = (const float*)d_in[4];
    const float* qkv_w   = (const float*)d_in[5];
    const float* qkv_b   = (const float*)d_in[6];
    const float* out_w   = (const float*)d_in[7];
    const float* out_b   = (const float*)d_in[8];
    const float* ff1_w   = (const float*)d_in[9];
    const float* ff1_b   = (const float*)d_in[10];
    const float* ff2_w   = (const float*)d_in[11];
    const float* ff2_b   = (const float*)d_in[12];
    const float* ln1_g   = (const float*)d_in[13];
    const float* ln1_b   = (const float*)d_in[14];
    const float* ln2_g   = (const float*)d_in[15];
    const float* ln2_b   = (const float*)d_in[16];

    char* p = (char*)d_ws;
    float* pwT  = (float*)p;  p += (size_t)32 * D_ * 4;
    bf16* xb    = (bf16*)p;   p += (size_t)NTOK * D_ * 2;
    bf16* dpar  = (bf16*)p;   p += (size_t)2 * NTOK * D_ * 2;   // split-K partials
    bf16* qkvb  = (bf16*)p;   p += (size_t)NTOK * 3 * D_ * 2;
    bf16* hbuf  = (bf16*)p;   p += (size_t)NTOK * FF_ * 2;
    bf16* abuf  = (bf16*)p;   p += (size_t)NTOK * D_ * 2;
    // weights: contiguous wq | wo | w1 | w2 (prep_kernel relies on this)
    bf16* wq    = (bf16*)p;   p += (size_t)L_ * 3 * D_ * D_ * 2;
    bf16* wo    = (bf16*)p;   p += (size_t)L_ * D_ * D_ * 2;
    bf16* w1    = (bf16*)p;   p += (size_t)L_ * FF_ * D_ * 2;
    bf16* w2    = (bf16*)p;   p += (size_t)L_ * D_ * FF_ * 2;
    float* outp = (float*)d_out;

    prep_kernel<<<12288 + 64, 256, 0, stream>>>(
        qkv_w, out_w, ff1_w, ff2_w, wq, proj_w, pwT);

    proj_kernel<<<NTOK / 16, 256, 0, stream>>>(feat, pwT, proj_b, pos_enc, xb);

    for (int l = 0; l < L_; l++) {
        // QKV projection (unsplit)
        gemm_bf16_kernel<0><<<dim3(3 * D_ / 128, NTOK / 128, 1), 256, 0, stream>>>(
            (const short*)xb, (const short*)(wq + (size_t)l * 3 * D_ * D_),
            qkv_b + (size_t)l * 3 * D_, qkvb, NTOK, 3 * D_, D_, D_);
        attn_kernel<<<dim3(T_ / 64, B_ * H_), 256, 0, stream>>>((const short*)qkvb, abuf);
        // out-proj, split-K x2
        gemm_bf16_kernel<0><<<dim3(D_ / 128, NTOK / 128, 2), 256, 0, stream>>>(
            (const short*)abuf, (const short*)(wo + (size_t)l * D_ * D_),
            out_b + (size_t)l * D_, dpar, NTOK, D_, D_, D_ / 2);
        add_ln_kernel<<<NTOK / 4, 256, 0, stream>>>(
            (const short*)xb, (const short*)dpar, (const short*)(dpar + (size_t)NTOK * D_),
            ln1_g + (size_t)l * D_, ln1_b + (size_t)l * D_, xb, nullptr);
        // FF1 + ReLU (unsplit)
        gemm_bf16_kernel<1><<<dim3(FF_ / 128, NTOK / 128, 1), 256, 0, stream>>>(
            (const short*)xb, (const short*)(w1 + (size_t)l * FF_ * D_),
            ff1_b + (size_t)l * FF_, hbuf, NTOK, FF_, D_, D_);
        // FF2, split-K x2
        gemm_bf16_kernel<0><<<dim3(D_ / 128, NTOK / 128, 2), 256, 0, stream>>>(
            (const short*)hbuf, (const short*)(w2 + (size_t)l * D_ * FF_),
            ff2_b + (size_t)l * D_, dpar, NTOK, D_, FF_, FF_ / 2);
        float* dst = (l == L_ - 1) ? outp : nullptr;
        add_ln_kernel<<<NTOK / 4, 256, 0, stream>>>(
            (const short*)xb, (const short*)dpar, (const short*)(dpar + (size_t)NTOK * D_),
            ln2_g + (size_t)l * D_, ln2_b + (size_t)l * D_, xb, dst);
    }
}